// Round 6
// baseline (468.740 us; speedup 1.0000x reference)
//
#include <hip/hip_runtime.h>

// =====================================================================
// GraphAutoEncoder forward. GCN via CSR build + gather (unchanged).
// R14: split-bf16 MFMA GEMM landed but MfmaUtil=6%: 12 ds_read_b128 per
// 24 MFMAs -> 4 SIMDs share 1 LDS pipe -> 20% ceiling, latency gaps to
// 6%. R15: (a) W pre-split ONCE into global bf16 hi/lo planes (tiny
// kernel); B-fragments load global->VGPR directly (L1/L2-resident, no
// LDS cycles, no per-block split). (b) wave tile 64x64 (MF=NF=4): 8
// A-plane reads per 48 MFMAs -> per-CU MfmaUtil ceiling ~61%. (c) LDS
// 55->37KB (A planes only) -> 4 blocks/CU.
// =====================================================================

constexpr int NBLK = 128;           // scatter blocks (chunk = E/128)
constexpr int GRP  = NBLK / 8;      // block-groups per XCD residue

typedef __attribute__((ext_vector_type(8))) short bf16x8;
typedef __attribute__((ext_vector_type(4))) float f32x4;

// split two fp32 into packed-bf16 hi pair + lo pair (truncation split;
// hi = top 16 bits, lo = bf16(f - hi), residual <= 2^-16 |f|)
__device__ inline void split2(float f0, float f1, unsigned& hp, unsigned& lp) {
    unsigned u0 = __float_as_uint(f0), u1 = __float_as_uint(f1);
    hp = (u1 & 0xFFFF0000u) | (u0 >> 16);
    float r0 = f0 - __uint_as_float(u0 & 0xFFFF0000u);
    float r1 = f1 - __uint_as_float(u1 & 0xFFFF0000u);
    lp = (__float_as_uint(r1) & 0xFFFF0000u) | (__float_as_uint(r0) >> 16);
}

// ---------------- weight pre-split: fp32 -> bf16 hi/lo planes --------
struct WSplitArgs {
    const float* src[6];
    unsigned short* hi[6];
    unsigned short* lo[6];
    int n[6];
};
__global__ __launch_bounds__(256) void split_w(WSplitArgs a) {
    const int L = blockIdx.y;
    const int i = blockIdx.x * 256 + threadIdx.x;
    if (i < a.n[L]) {
        float f = a.src[L][i];
        unsigned u = __float_as_uint(f);
        float r = f - __uint_as_float(u & 0xFFFF0000u);
        a.hi[L][i] = (unsigned short)(u >> 16);
        a.lo[L][i] = (unsigned short)(__float_as_uint(r) >> 16);
    }
}

// ---------------- GEMM: C[:,foff:+BN] = act(A @ W^T + b), MFMA -------
// A [N][K] fp32 (split in-kernel to LDS planes). W pre-split planes
// [M][K] ushort. 256 thr = 4 waves, wave tile (MF*16) x (NF*16).
// BM = WM*MF*16 = 128 nodes. grid = (391, M/BN).
template <int K, int M, int ACT, bool BIAS, int WM, int WN, int MF, int NF>
__global__ __launch_bounds__(256) void gemm_bd(const float* __restrict__ A,
                                               const unsigned short* __restrict__ Whp,
                                               const unsigned short* __restrict__ Wlp,
                                               const float* __restrict__ bias,
                                               float* __restrict__ C, int N) {
    static_assert(K % 64 == 0, "K%64");
    static_assert(WM * WN == 4, "4 waves");
    static_assert(WM * MF * 16 == 128, "BM=128");
    constexpr int KC = 64;
    constexpr int BN = WN * NF * 16;
    // uint = 2 bf16 along k; rows 32 uints + 4 pad (2-way bank alias = free)
    __shared__ unsigned Ah[128][36];
    __shared__ unsigned Al[128][36];

    const int tid      = threadIdx.x;
    const int nodeBase = blockIdx.x * 128;
    const int foff     = blockIdx.y * BN;

    // staging map: row = q*16 + (tid>>4), float4 col = tid&15 (64 k/row)
    const int srow = tid >> 4;
    const int sc4  = tid & 15;
    float4 av[8];

#pragma unroll
    for (int q = 0; q < 8; ++q) {
        const int gn = nodeBase + q * 16 + srow;
        av[q] = (gn < N) ? *(const float4*)(A + (size_t)gn * K + sc4 * 4)
                         : make_float4(0.f, 0.f, 0.f, 0.f);
    }

    f32x4 acc[MF][NF];
#pragma unroll
    for (int mf = 0; mf < MF; ++mf)
#pragma unroll
        for (int nf = 0; nf < NF; ++nf) acc[mf][nf] = (f32x4)0.f;

    const int lane = tid & 63;
    const int wid  = tid >> 6;
    const int wm   = wid / WN;
    const int wn   = wid % WN;
    const int fr   = lane & 15;
    const int fg   = lane >> 4;

    for (int kc = 0; kc < K; kc += KC) {
        // commit staged regs -> LDS bf16 planes (A only)
#pragma unroll
        for (int q = 0; q < 8; ++q) {
            unsigned h0, l0, h1, l1;
            split2(av[q].x, av[q].y, h0, l0);
            split2(av[q].z, av[q].w, h1, l1);
            const int r = q * 16 + srow;
            Ah[r][sc4 * 2] = h0; Ah[r][sc4 * 2 + 1] = h1;
            Al[r][sc4 * 2] = l0; Al[r][sc4 * 2 + 1] = l1;
        }
        __syncthreads();

        // prefetch next A tile (drains during MFMA below)
        if (kc + KC < K) {
#pragma unroll
            for (int q = 0; q < 8; ++q) {
                const int gn = nodeBase + q * 16 + srow;
                av[q] = (gn < N)
                    ? *(const float4*)(A + (size_t)gn * K + kc + KC + sc4 * 4)
                    : make_float4(0.f, 0.f, 0.f, 0.f);
            }
        }

#pragma unroll
        for (int kf = 0; kf < 2; ++kf) {
            // B fragments: direct global (L1/L2-resident planes), no LDS
            bf16x8 bh[NF], bl[NF];
#pragma unroll
            for (int nf = 0; nf < NF; ++nf) {
                const size_t wo = (size_t)(foff + wn * NF * 16 + nf * 16 + fr) * K
                                  + kc + kf * 32 + fg * 8;
                bh[nf] = *(const bf16x8*)(Whp + wo);
                bl[nf] = *(const bf16x8*)(Wlp + wo);
            }
            bf16x8 ah[MF], alo[MF];
#pragma unroll
            for (int mf = 0; mf < MF; ++mf) {
                const int r = wm * MF * 16 + mf * 16 + fr;
                ah[mf]  = *(const bf16x8*)&Ah[r][kf * 16 + fg * 4];
                alo[mf] = *(const bf16x8*)&Al[r][kf * 16 + fg * 4];
            }
#pragma unroll
            for (int mf = 0; mf < MF; ++mf)
#pragma unroll
                for (int nf = 0; nf < NF; ++nf) {
                    acc[mf][nf] = __builtin_amdgcn_mfma_f32_16x16x32_bf16(
                        ah[mf], bh[nf], acc[mf][nf], 0, 0, 0);
                    acc[mf][nf] = __builtin_amdgcn_mfma_f32_16x16x32_bf16(
                        alo[mf], bh[nf], acc[mf][nf], 0, 0, 0);
                    acc[mf][nf] = __builtin_amdgcn_mfma_f32_16x16x32_bf16(
                        ah[mf], bl[nf], acc[mf][nf], 0, 0, 0);
                }
        }
        __syncthreads();
    }

    // epilogue: D[row=(lane>>4)*4+i][col=lane&15] per frag
#pragma unroll
    for (int nf = 0; nf < NF; ++nf) {
        const int feat = foff + wn * NF * 16 + nf * 16 + fr;
        const float bv = BIAS ? bias[feat] : 0.f;
#pragma unroll
        for (int mf = 0; mf < MF; ++mf) {
            const int node0 = nodeBase + wm * MF * 16 + mf * 16 + fg * 4;
#pragma unroll
            for (int i = 0; i < 4; ++i) {
                const int node = node0 + i;
                if (node < N) {
                    float x = acc[mf][nf][i] + bv;
                    if constexpr (ACT == 1) x = fmaxf(x, 0.f);
                    if constexpr (ACT == 2) x = 1.f / (1.f + __expf(-x));
                    C[(size_t)node * M + feat] = x;
                }
            }
        }
    }
}

// ---------------- CSR build: deterministic counting sort -------------
// bucket b = dst >> 6; count index = b*128 + r*16 + g  (r = blockIdx&7,
// g = blockIdx>>3) => bucketBase[b] = pos[b*128]. Zero global atomics.

__global__ __launch_bounds__(256) void count_k(const int* __restrict__ ei,
                                               int* __restrict__ cnt,
                                               int NB, int E) {
    __shared__ int hist[784];
    const int tid = threadIdx.x;
    for (int i = tid; i < NB; i += 256) hist[i] = 0;
    __syncthreads();
    const int chunk = (E + NBLK - 1) / NBLK;
    const int lo = blockIdx.x * chunk;
    const int hi = min(lo + chunk, E);
    for (int e = lo + tid; e < hi; e += 256) {
        int d = ei[E + e];
        atomicAdd(&hist[d >> 6], 1);
    }
    __syncthreads();
    const int r = blockIdx.x & 7, g = blockIdx.x >> 3;
    for (int i = tid; i < NB; i += 256)
        cnt[i * NBLK + r * GRP + g] = hist[i];
}

__global__ __launch_bounds__(256) void scan1(const int* __restrict__ cnt,
                                             int* __restrict__ pos,
                                             int* __restrict__ bs, int n) {
    __shared__ int s[256];
    const int t = threadIdx.x;
    const int i0 = blockIdx.x * 512 + 2 * t;
    int c0 = (i0     < n) ? cnt[i0]     : 0;
    int c1 = (i0 + 1 < n) ? cnt[i0 + 1] : 0;
    int c = c0 + c1;
    s[t] = c;
    __syncthreads();
    for (int off = 1; off < 256; off <<= 1) {
        int v = (t >= off) ? s[t - off] : 0;
        __syncthreads();
        s[t] += v;
        __syncthreads();
    }
    int excl = s[t] - c;
    if (i0     < n) pos[i0]     = excl;
    if (i0 + 1 < n) pos[i0 + 1] = excl + c0;
    if (t == 255) bs[blockIdx.x] = s[255];
}

__global__ __launch_bounds__(256) void scan_tops(int* __restrict__ bs, int nb) {
    __shared__ int s[256];
    int t = threadIdx.x;
    int v = (t < nb) ? bs[t] : 0;
    s[t] = v;
    __syncthreads();
    for (int off = 1; off < 256; off <<= 1) {
        int u = (t >= off) ? s[t - off] : 0;
        __syncthreads();
        s[t] += u;
        __syncthreads();
    }
    if (t < nb) bs[t] = s[t] - v;
}

__global__ __launch_bounds__(256) void scan2(int* __restrict__ pos,
                                             const int* __restrict__ bs,
                                             int* __restrict__ bucketBase,
                                             int n, int NB, int E) {
    const int t = threadIdx.x;
    const int i0 = blockIdx.x * 512 + 2 * t;
    const int add = bs[blockIdx.x];
#pragma unroll
    for (int c = 0; c < 2; ++c) {
        int i = i0 + c;
        if (i < n) {
            int v = pos[i] + add;
            pos[i] = v;
            if ((i & (NBLK - 1)) == 0) bucketBase[i >> 7] = v;
        }
    }
    if (blockIdx.x == 0 && t == 0) bucketBase[NB] = E;
}

__global__ __launch_bounds__(256) void place_k(const int* __restrict__ ei,
                                               const float* __restrict__ w,
                                               const int* __restrict__ pos,
                                               int2* __restrict__ ebuf,
                                               int NB, int E) {
    __shared__ int cur[784];
    const int tid = threadIdx.x;
    const int r = blockIdx.x & 7, g = blockIdx.x >> 3;
    for (int i = tid; i < NB; i += 256) cur[i] = pos[i * NBLK + r * GRP + g];
    __syncthreads();
    const int chunk = (E + NBLK - 1) / NBLK;
    const int lo = blockIdx.x * chunk;
    const int hi = min(lo + chunk, E);
    for (int e = lo + tid; e < hi; e += 256) {
        int s = ei[e];
        int d = ei[E + e];
        float wv = w[e];
        int p = atomicAdd(&cur[d >> 6], 1);  // LDS atomic
        ebuf[p] = make_int2(s | ((d & 63) << 26), __float_as_int(wv));
    }
}

__global__ __launch_bounds__(256) void bucket_build(const int2* __restrict__ ebuf,
                                                    const int* __restrict__ bucketBase,
                                                    int2* __restrict__ sn,
                                                    int* __restrict__ row,
                                                    float* __restrict__ dinv,
                                                    int N, int E) {
    __shared__ int   lh[64];
    __shared__ float ldg[64];
    __shared__ int   sc[64];
    __shared__ int   lofs[64];
    const int tid  = threadIdx.x;
    const int base = bucketBase[blockIdx.x];
    const int end  = bucketBase[blockIdx.x + 1];

    if (tid < 64) { lh[tid] = 0; ldg[tid] = 0.f; }
    __syncthreads();
    for (int i = base + tid; i < end; i += 256) {
        int2 v = ebuf[i];
        int dl = ((unsigned)v.x) >> 26;
        atomicAdd(&lh[dl], 1);
        atomicAdd(&ldg[dl], __int_as_float(v.y));
    }
    __syncthreads();
    if (tid < 64) sc[tid] = lh[tid];
    __syncthreads();
    for (int off = 1; off < 64; off <<= 1) {
        int v = (tid < 64 && tid >= off) ? sc[tid - off] : 0;
        __syncthreads();
        if (tid < 64) sc[tid] += v;
        __syncthreads();
    }
    if (tid < 64) {
        int excl = sc[tid] - lh[tid];
        int d = (blockIdx.x << 6) + tid;
        if (d < N) {
            row[d]  = base + excl;
            dinv[d] = rsqrtf(fmaxf(1.0f + ldg[tid], 1e-12f));  // + self-loop
        }
        lofs[tid] = base + excl;
    }
    __syncthreads();
    for (int i = base + tid; i < end; i += 256) {
        int2 v = ebuf[i];
        unsigned u = (unsigned)v.x;
        int dl = u >> 26;
        int s  = u & 0x03FFFFFF;
        int p  = atomicAdd(&lofs[dl], 1);
        sn[p] = make_int2(s, v.y);
    }
    if (blockIdx.x == 0 && tid == 0) row[N] = E;
}

// payload.y <- w * dinv[src]
__global__ __launch_bounds__(256) void scale_pay(int2* __restrict__ sn,
                                                 const float* __restrict__ dinv,
                                                 int E) {
    int p = blockIdx.x * 256 + threadIdx.x;
    if (p < E) {
        int2 v = sn[p];
        sn[p] = make_int2(v.x, __float_as_int(__int_as_float(v.y) * dinv[v.x]));
    }
}

// ---------------- fused GCN aggregation (gather, no atomics) ---------
// out[i] = relu( (sum_e pay_e*t[src_e] + t[i]*dinv[i]) * dinv[i] + b )
__global__ __launch_bounds__(256) void gcn_agg(const float* __restrict__ t,
                                               const int2* __restrict__ sn,
                                               const int* __restrict__ row,
                                               const float* __restrict__ dinv,
                                               const float* __restrict__ bias,
                                               float* __restrict__ out, int N) {
    const int lane = threadIdx.x & 63;
    int i = __builtin_amdgcn_readfirstlane((int)(blockIdx.x * 4) + (threadIdx.x >> 6));
    if (i >= N) return;
    float di   = dinv[i];
    float self = t[(size_t)i * 64 + lane];
    float acc  = 0.f;
    int p  = row[i];
    int pe = row[i + 1];
    for (; p + 4 <= pe; p += 4) {
        int2 v0 = sn[p];
        int2 v1 = sn[p + 1];
        int2 v2 = sn[p + 2];
        int2 v3 = sn[p + 3];
        acc += t[(size_t)v0.x * 64 + lane] * __int_as_float(v0.y);
        acc += t[(size_t)v1.x * 64 + lane] * __int_as_float(v1.y);
        acc += t[(size_t)v2.x * 64 + lane] * __int_as_float(v2.y);
        acc += t[(size_t)v3.x * 64 + lane] * __int_as_float(v3.y);
    }
    for (; p < pe; ++p) {
        int2 v = sn[p];
        acc += t[(size_t)v.x * 64 + lane] * __int_as_float(v.y);
    }
    float x = (acc + self * di) * di + bias[lane];
    out[(size_t)i * 64 + lane] = fmaxf(x, 0.f);
}

// =====================================================================
extern "C" void kernel_launch(void* const* d_in, const int* in_sizes, int n_in,
                              void* d_out, int out_size, void* d_ws, size_t ws_size,
                              hipStream_t stream) {
    const float* x      = (const float*)d_in[0];
    const int*   ei     = (const int*)d_in[1];   // int32 per harness contract
    const float* ew     = (const float*)d_in[2];
    const float* enc1_w = (const float*)d_in[3];
    const float* enc1_b = (const float*)d_in[4];
    const float* enc2_w = (const float*)d_in[5];
    const float* enc2_b = (const float*)d_in[6];
    const float* gcn1_w = (const float*)d_in[7];
    const float* gcn1_b = (const float*)d_in[8];
    const float* gcn2_w = (const float*)d_in[9];
    const float* gcn2_b = (const float*)d_in[10];
    const float* dec1_w = (const float*)d_in[11];
    const float* dec1_b = (const float*)d_in[12];
    const float* dec2_w = (const float*)d_in[13];
    const float* dec2_b = (const float*)d_in[14];

    const int N  = in_sizes[0] / 256;    // 50000
    const int E  = in_sizes[2];          // 1600000
    const int NB = (N + 63) / 64;        // 782 buckets
    const int NCNT = NB * NBLK;          // 100096 counters
    const int NS   = (NCNT + 511) / 512; // 196 scan blocks

    // workspace (~40 MB):
    //  bufA [N*128 floats]: h1 -> { sn[E] int2 | ebuf[E] int2 (=bufC) } -> h5
    //  bufB [N*64]: h2/h3/h4 ; dinv[N]; row[N+1];
    //  cnt[NCNT]; pos[NCNT]; bucketBase[NB+1]; bs[256]; W split planes
    float* ws   = (float*)d_ws;
    float* bufA = ws;
    int2*  sn   = (int2*)bufA;                  // E int2 (first half of bufA)
    float* bufC = bufA + (size_t)2 * E;         // N*64 floats (second half)
    int2*  ebuf = (int2*)bufC;                  // aliases bufC during build
    float* bufB = bufA + (size_t)N * 128;       // N*64
    float* dinv = bufB + (size_t)N * 64;        // N
    int*   row  = (int*)(dinv + N);             // N+1
    int*   cnt  = row + (N + 1);                // NCNT
    int*   pos  = cnt + NCNT;                   // NCNT
    int*   bucketBase = pos + NCNT;             // NB+1
    int*   bs   = bucketBase + (NB + 1);        // 256
    // W split planes (90112 elements per plane); 16B-aligned by layout
    unsigned short* whi = (unsigned short*)(bs + 256);
    unsigned short* wlo = whi + 90112;
    // per-layer element offsets: enc1 0, enc2 32768, gcn1 40960,
    // gcn2 45056, dec1 49152, dec2 57344 (all *2B % 16 == 0)

    const int gemmGrid = (N + 127) / 128;       // 391
    const int nBlkE    = (E + 255) / 256;       // 6250

    // weight pre-split (runs once, ~360KB traffic)
    WSplitArgs wa;
    const float* wsrc[6] = {enc1_w, enc2_w, gcn1_w, gcn2_w, dec1_w, dec2_w};
    const int    wsz[6]  = {32768, 8192, 4096, 4096, 8192, 32768};
    const int    woff[6] = {0, 32768, 40960, 45056, 49152, 57344};
    for (int l = 0; l < 6; ++l) {
        wa.src[l] = wsrc[l];
        wa.hi[l]  = whi + woff[l];
        wa.lo[l]  = wlo + woff[l];
        wa.n[l]   = wsz[l];
    }
    split_w<<<dim3(128, 6), 256, 0, stream>>>(wa);

    // encoder
    gemm_bd<256, 128, 1, true, 2, 2, 4, 4><<<dim3(gemmGrid, 1), 256, 0, stream>>>(
        x, whi + woff[0], wlo + woff[0], enc1_b, bufA, N);
    gemm_bd<128, 64, 1, true, 4, 1, 2, 4><<<dim3(gemmGrid, 1), 256, 0, stream>>>(
        bufA, whi + woff[1], wlo + woff[1], enc2_b, bufB, N);

    // CSR build, zero global atomics (shared by both GCN layers)
    count_k<<<NBLK, 256, 0, stream>>>(ei, cnt, NB, E);
    scan1<<<NS, 256, 0, stream>>>(cnt, pos, bs, NCNT);
    scan_tops<<<1, 256, 0, stream>>>(bs, NS);
    scan2<<<NS, 256, 0, stream>>>(pos, bs, bucketBase, NCNT, NB, E);
    place_k<<<NBLK, 256, 0, stream>>>(ei, ew, pos, ebuf, NB, E);
    bucket_build<<<NB, 256, 0, stream>>>(ebuf, bucketBase, sn, row, dinv, N, E);
    scale_pay<<<nBlkE, 256, 0, stream>>>(sn, dinv, E);

    // GCN layer 1
    gemm_bd<64, 64, 0, false, 4, 1, 2, 4><<<dim3(gemmGrid, 1), 256, 0, stream>>>(
        bufB, whi + woff[2], wlo + woff[2], nullptr, bufC, N);
    gcn_agg<<<(N + 3) / 4, 256, 0, stream>>>(bufC, sn, row, dinv, gcn1_b, bufB, N);

    // GCN layer 2
    gemm_bd<64, 64, 0, false, 4, 1, 2, 4><<<dim3(gemmGrid, 1), 256, 0, stream>>>(
        bufB, whi + woff[3], wlo + woff[3], nullptr, bufC, N);
    gcn_agg<<<(N + 3) / 4, 256, 0, stream>>>(bufC, sn, row, dinv, gcn2_b, bufB, N);

    // decoder
    gemm_bd<64, 128, 1, true, 2, 2, 4, 4><<<dim3(gemmGrid, 1), 256, 0, stream>>>(
        bufB, whi + woff[4], wlo + woff[4], dec1_b, bufA, N);
    gemm_bd<128, 256, 2, true, 2, 2, 4, 4><<<dim3(gemmGrid, 2), 256, 0, stream>>>(
        bufA, whi + woff[5], wlo + woff[5], dec2_b, (float*)d_out, N);
}